// Round 7
// baseline (292.030 us; speedup 1.0000x reference)
//
#include <hip/hip_runtime.h>
#include <hip/hip_bf16.h>
#include <math.h>

// attention scale folded with log2(e) for exp2-based softmax:
// q_attn = q * (256^-0.5 * log2(e))
#define QSC 0.09016844f

typedef __attribute__((ext_vector_type(8))) short bf16x8;
typedef __attribute__((ext_vector_type(4))) float f32x4;

// fp32 -> bf16 round-to-nearest-even
__device__ __forceinline__ ushort f2bf(float f) {
    unsigned u = __float_as_uint(f);
    return (ushort)((u + 0x7FFFu + ((u >> 16) & 1u)) >> 16);
}

__device__ __forceinline__ unsigned pk2bf(float a, float b) {
    __hip_bfloat162 h = __float22bfloat162_rn(make_float2(a, b));
    return *(unsigned*)&h;
}

// async global->LDS, 16B per lane. LDS dest must be wave-uniform base + lane*16.
__device__ __forceinline__ void gl_lds16(const ushort* g, ushort* l) {
    __builtin_amdgcn_global_load_lds(
        (const __attribute__((address_space(1))) unsigned int*)g,
        (__attribute__((address_space(3))) unsigned int*)l, 16, 0, 0);
}

// XOR swizzle for DMA-staged [row][4x8ushort] tiles: kills the 8-way
// fragment-read conflict (row stride 64B) without padding.
__device__ __forceinline__ int swz(int row) { return (row ^ (row >> 2)) & 3; }

// ---------------------------------------------------------------------------
// K1: merged prep. Blocks [0,784): window-gather cast x->xg (bf16, window
// order) + fp32 window means (one pass over x). Blocks [784,1808): weight
// transpose+cast.
// ---------------------------------------------------------------------------
__global__ __launch_bounds__(256) void k_prep(const float* __restrict__ x,
                                              const float* __restrict__ Wqkv,
                                              const float* __restrict__ Wo,
                                              ushort* __restrict__ xg,
                                              float* __restrict__ xmean,
                                              ushort* __restrict__ Wqkvt,
                                              ushort* __restrict__ Wot) {
    int b = blockIdx.x;
    int tid = threadIdx.x;
    if (b >= 784) {
        int bb = b - 784;
        if (bb < 768) Wqkvt[bb * 256 + tid] = f2bf(Wqkv[(size_t)tid * 768 + bb]);
        else { int n = bb - 768; Wot[n * 256 + tid] = f2bf(Wo[(size_t)tid * 256 + n]); }
        return;
    }
    int nd = b / 49, p = b % 49;
    int j = p / 7, i = p % 7;
    const float* xb = x + ((size_t)nd * 3136 + (j * 8) * 56 + i * 8) * 256 + tid;
    ushort* xo = xg + (size_t)b * 64 * 256 + tid;
    float s = 0.f;
#pragma unroll 2
    for (int hh = 0; hh < 8; ++hh)
#pragma unroll
        for (int ww = 0; ww < 8; ++ww) {
            float v = xb[(size_t)(hh * 56 + ww) * 256];
            s += v;
            xo[(size_t)(hh * 8 + ww) * 256] = f2bf(v);
        }
    xmean[(size_t)b * 256 + tid] = s * (1.f / 64.f);
}

// ---------------------------------------------------------------------------
// Routing projection, pure fp32 (decoupled from bf16 numerics).
// ---------------------------------------------------------------------------
__global__ __launch_bounds__(256) void k_winproj(const float* __restrict__ xmean,
                                                 const float* __restrict__ Wqkv,
                                                 const float* __restrict__ bqkv,
                                                 float* __restrict__ qwin,
                                                 float* __restrict__ kwin) {
    __shared__ float As[16 * 68];
    __shared__ float Bs[16 * 64];
    const int tid = threadIdx.x;
    const int m0 = blockIdx.y * 64;
    const int n0 = blockIdx.x * 64;

    const int ar = tid >> 2;
    const int ak = (tid & 3) * 4;
    const int arow = (m0 + ar < 784) ? (m0 + ar) : 783;
    const float* aptr = xmean + (size_t)arow * 256 + ak;

    const int bk = tid >> 4;
    const int bn = (tid & 15) * 4;
    const float* bptr = Wqkv + (size_t)bk * 768 + n0 + bn;

    const int ty = tid >> 4, tx = tid & 15;
    float acc[4][4] = {};

    for (int kt = 0; kt < 256; kt += 16) {
        float4 av = *(const float4*)(aptr + kt);
        float4 bv = *(const float4*)(bptr + (size_t)kt * 768);
        __syncthreads();
        As[(ak + 0) * 68 + ar] = av.x;
        As[(ak + 1) * 68 + ar] = av.y;
        As[(ak + 2) * 68 + ar] = av.z;
        As[(ak + 3) * 68 + ar] = av.w;
        *(float4*)&Bs[bk * 64 + bn] = bv;
        __syncthreads();
#pragma unroll
        for (int kk = 0; kk < 16; ++kk) {
            float4 a4 = *(const float4*)&As[kk * 68 + ty * 4];
            float4 b4 = *(const float4*)&Bs[kk * 64 + tx * 4];
            float a[4] = {a4.x, a4.y, a4.z, a4.w};
            float b[4] = {b4.x, b4.y, b4.z, b4.w};
#pragma unroll
            for (int ii = 0; ii < 4; ++ii)
#pragma unroll
                for (int jj = 0; jj < 4; ++jj) acc[ii][jj] += a[ii] * b[jj];
        }
    }
#pragma unroll
    for (int ii = 0; ii < 4; ++ii) {
        int t = m0 + ty * 4 + ii;
        if (t >= 784) continue;
#pragma unroll
        for (int jj = 0; jj < 4; ++jj) {
            int col = n0 + tx * 4 + jj;
            float v = acc[ii][jj] + bqkv[col];
            if (col < 256) qwin[(size_t)t * 256 + col] = v;
            else           kwin[(size_t)t * 256 + (col - 256)] = v;
        }
    }
}

// ---------------------------------------------------------------------------
// Routing top-k. 4 waves split the 256-channel dot product (float4 loads),
// LDS partial reduce, wave 0 does the top-4 selection.
// ---------------------------------------------------------------------------
__global__ __launch_bounds__(256) void k_route(const float* __restrict__ qwin,
                                               const float* __restrict__ kwin,
                                               int* __restrict__ ridx) {
    const int b = blockIdx.x;                 // nd*49 + p
    const int nd = b / 49;
    const int ndkv = ((nd & 7) == 7) ? nd : nd + 1;
    const int tid = threadIdx.x;
    const int t = tid & 63, w = tid >> 6;
    __shared__ float qs[256];
    __shared__ float part[4][64];
    qs[tid] = qwin[b * 256 + tid];
    __syncthreads();
    float s = 0.f;
    if (t < 49) {
        const float* kr = kwin + ((size_t)ndkv * 49 + t) * 256 + w * 64;
#pragma unroll
        for (int c = 0; c < 64; c += 4) {
            float4 k4 = *(const float4*)(kr + c);
            float4 q4 = *(const float4*)&qs[w * 64 + c];
            s += q4.x * k4.x + q4.y * k4.y + q4.z * k4.z + q4.w * k4.w;
        }
    }
    part[w][t] = s;
    __syncthreads();
    if (tid < 64) {
        float logit = (t < 49) ? (part[0][t] + part[1][t] + part[2][t] + part[3][t])
                               : -INFINITY;
        for (int sel = 0; sel < 4; ++sel) {
            float v = logit;
            int ix = t;
            for (int off = 32; off > 0; off >>= 1) {
                float ov = __shfl_xor(v, off);
                int   oi = __shfl_xor(ix, off);
                if (ov > v || (ov == v && oi < ix)) { v = ov; ix = oi; }
            }
            if (t == 0) ridx[b * 4 + sel] = ix;
            if (t == ix) logit = -INFINITY;
        }
    }
}

// ---------------------------------------------------------------------------
// K2: bf16 MFMA GEMM, 128x128 tile, BK=32, 2-phase double-buffered
// direct-to-LDS staging for BOTH A and B (R6's B-from-global regressed:
// per-step L2 latency on the barriered critical path). 32 KB LDS.
// XCD-chunked swizzle keeps the 6 N-tiles sharing an A-panel on one XCD L2.
// ---------------------------------------------------------------------------
__global__ __launch_bounds__(256) void k_gemm_qkv(const ushort* __restrict__ A,
                                                  const ushort* __restrict__ Bt,
                                                  const float* __restrict__ bqkv,
                                                  ushort* __restrict__ q,
                                                  ushort* __restrict__ kv) {
    __shared__ ushort As[2][128 * 32];
    __shared__ ushort Bs[2][128 * 32];
    const int tid = threadIdx.x;
    const int wv = tid >> 6, ln = tid & 63;
    const int lane15 = ln & 15, quad = ln >> 4;

    // bijective XCD swizzle: nwg = 2352 = 8 * 294.
    const int lin  = blockIdx.x + blockIdx.y * 6;
    const int work = (lin & 7) * 294 + (lin >> 3);
    const int n0 = (work % 6) * 128;
    const int m0 = (work / 6) * 128;

    const int row0 = tid >> 2, ck0 = tid & 3;
    const ushort* gA[2]; const ushort* gB[2];
    int lofs[2];
#pragma unroll
    for (int p = 0; p < 2; ++p) {
        int r = p * 64 + row0;
        int cks = ck0 ^ swz(r);               // swizzled chunk this lane stages
        gA[p] = A  + (size_t)(m0 + r) * 256 + cks * 8;
        gB[p] = Bt + (size_t)(n0 + r) * 256 + cks * 8;
        lofs[p] = (p * 256 + tid) * 8;
    }

    f32x4 acc[4][4];
#pragma unroll
    for (int i = 0; i < 4; ++i)
#pragma unroll
        for (int j = 0; j < 4; ++j) acc[i][j] = (f32x4){0.f, 0.f, 0.f, 0.f};

    const int mb = (wv >> 1) * 64, nb = (wv & 1) * 64;

    // prologue: stage K-tile 0 into buf 0
#pragma unroll
    for (int p = 0; p < 2; ++p) {
        gl_lds16(gA[p], &As[0][lofs[p]]);
        gl_lds16(gB[p], &Bs[0][lofs[p]]);
    }
    asm volatile("s_waitcnt vmcnt(0)" ::: "memory");
    __builtin_amdgcn_s_barrier();

    int cur = 0;
#pragma unroll
    for (int kt = 0; kt < 8; ++kt) {
        if (kt < 7) {                          // issue next tile's loads first
#pragma unroll
            for (int p = 0; p < 2; ++p) {
                gl_lds16(gA[p] + (kt + 1) * 32, &As[cur ^ 1][lofs[p]]);
                gl_lds16(gB[p] + (kt + 1) * 32, &Bs[cur ^ 1][lofs[p]]);
            }
        }
        __builtin_amdgcn_sched_barrier(0);
        bf16x8 aF[4], bF[4];
#pragma unroll
        for (int mt = 0; mt < 4; ++mt) {
            int r = mb + mt * 16 + lane15;
            aF[mt] = *(const bf16x8*)&As[cur][r * 32 + (quad ^ swz(r)) * 8];
        }
#pragma unroll
        for (int nt = 0; nt < 4; ++nt) {
            int r = nb + nt * 16 + lane15;
            bF[nt] = *(const bf16x8*)&Bs[cur][r * 32 + (quad ^ swz(r)) * 8];
        }
#pragma unroll
        for (int mt = 0; mt < 4; ++mt)
#pragma unroll
            for (int nt = 0; nt < 4; ++nt)
                acc[mt][nt] = __builtin_amdgcn_mfma_f32_16x16x32_bf16(aF[mt], bF[nt], acc[mt][nt], 0, 0, 0);
        __builtin_amdgcn_sched_barrier(0);
        asm volatile("s_waitcnt vmcnt(0)" ::: "memory");   // next tile landed
        __builtin_amdgcn_s_barrier();                      // all waves done reading cur
        cur ^= 1;
    }

#pragma unroll
    for (int mt = 0; mt < 4; ++mt) {
#pragma unroll
        for (int nt = 0; nt < 4; ++nt) {
            int col = n0 + nb + nt * 16 + lane15;
            float bias = bqkv[col];
#pragma unroll
            for (int r = 0; r < 4; ++r) {
                int t = m0 + mb + mt * 16 + quad * 4 + r;
                float v = acc[mt][nt][r] + bias;
                if (col < 256) q[(size_t)t * 256 + col] = f2bf(v * QSC);
                else           kv[(size_t)t * 512 + (col - 256)] = f2bf(v);
            }
        }
    }
}

// ---------------------------------------------------------------------------
// K3: FUSED attention + output projection. One block per (p, nd); 4 waves.
// Loops the 8 heads sequentially (R5's proven per-head staging: DMA'd K with
// XOR-chunk swizzle, VALU V-transpose, exp2 softmax with deferred norm),
// accumulating q' into LDS Qp[64][264] (padded: 528B row stride = 2-way bank
// alias, free). Then each wave computes its own 16 rows x 256 cols of the
// output projection from Qp (wave-own rows -> no extra sync) with Wot
// fragments straight from L2 (no barriers in this loop, so load latency
// pipelines freely), and scatters fp32 to out with the un-window mapping.
// Eliminates the q' HBM round-trip (51.4 MB) and the k_gemm_o launch.
// LDS: Ks 16K + Vt 16.5K + Ps 9K + Qp 33K = 74.5 KB -> 2 blocks/CU.
// ---------------------------------------------------------------------------
__global__ __launch_bounds__(256) void k_attn_o(const ushort* __restrict__ qbuf,
                                                const ushort* __restrict__ kvbuf,
                                                const int* __restrict__ ridx,
                                                const ushort* __restrict__ Wot,
                                                const float* __restrict__ bo,
                                                float* __restrict__ out) {
    // nwg = 784 = 8 * 98: chunk = 2 nd-bands x 49 p per XCD (kv band ~3.2 MB).
    const int lin  = blockIdx.x;
    const int work = (lin & 7) * 98 + (lin >> 3);
    const int p  = work % 49;
    const int nd = work / 49;

    const int ndkv = ((nd & 7) == 7) ? nd : nd + 1;
    const int tid = threadIdx.x;
    const int wv = tid >> 6, ln = tid & 63;
    const int lane15 = ln & 15, quad = ln >> 4;

    __shared__ ushort Ks[256 * 32];   // [key][32ch] linear, XOR-swizzled chunks
    __shared__ ushort Vt[32 * 264];   // [ch][key] stride 264: 16.5 KB
    __shared__ ushort Ps[64 * 72];    // [qrow][64key chunk]: 9 KB
    __shared__ ushort Qp[64 * 264];   // q' accumulator [pix][ch], padded: 33 KB

    const int rb = (nd * 49 + p) * 4;
    int wid[4];
#pragma unroll
    for (int i = 0; i < 4; ++i) wid[i] = ridx[rb + i];

    const size_t kvband = (size_t)ndkv * 49;
    const size_t qrow0  = (size_t)(nd * 49 + p) * 64;

    // per-lane constants for K staging / reading (proven in R5)
    const int key_l = wv * 16 + (ln >> 2);             // staged key
    const int ckst  = (ln ^ (ln >> 2) ^ (ln >> 4)) & 3; // (ln&3) ^ swz(key_l)
    const int ksz   = (lane15 ^ (lane15 >> 2)) & 3;     // read-side unswizzle
    // V staging lane map
    const int vkey  = (tid & 31) * 2;
    const int vch0  = (tid >> 5) * 4;

    for (int h = 0; h < 8; ++h) {
        if (h > 0) __builtin_amdgcn_s_barrier();   // all waves done reading Ks/Vt

        // ---- stage K via DMA: dest linear, source pre-swizzled ----
#pragma unroll
        for (int i = 0; i < 4; ++i) {
            size_t trow = (kvband + wid[i]) * 64 + key_l;
            gl_lds16(kvbuf + trow * 512 + h * 32 + ckst * 8,
                     &Ks[(i * 64 + wv * 16) * 32 + ln * 8]);
        }

        // ---- Q B-frag (wave's own 16 q-rows), hides under V staging ----
        bf16x8 bQ = *(const bf16x8*)(qbuf + (qrow0 + wv * 16 + lane15) * 256 + h * 32 + quad * 8);

        // ---- stage V transposed: Vt[ch][key] ----
#pragma unroll
        for (int i = 0; i < 4; ++i) {
            size_t trow = (kvband + wid[i]) * 64;
            const ushort* g0 = kvbuf + (trow + vkey) * 512 + 256 + h * 32 + vch0;
            const ushort* g1 = g0 + 512;
            ushort4 a = *(const ushort4*)g0;
            ushort4 b = *(const ushort4*)g1;
            int kg = i * 64 + vkey;
            *(unsigned*)&Vt[(vch0 + 0) * 264 + kg] = (unsigned)a.x | ((unsigned)b.x << 16);
            *(unsigned*)&Vt[(vch0 + 1) * 264 + kg] = (unsigned)a.y | ((unsigned)b.y << 16);
            *(unsigned*)&Vt[(vch0 + 2) * 264 + kg] = (unsigned)a.z | ((unsigned)b.z << 16);
            *(unsigned*)&Vt[(vch0 + 3) * 264 + kg] = (unsigned)a.w | ((unsigned)b.w << 16);
        }

        asm volatile("s_waitcnt vmcnt(0) lgkmcnt(0)" ::: "memory");
        __builtin_amdgcn_s_barrier();

        // ---- S^T = K · Q^T ----
        f32x4 st[16];
        __builtin_amdgcn_s_setprio(1);
#pragma unroll
        for (int t = 0; t < 16; ++t) {
            bf16x8 aK = *(const bf16x8*)&Ks[(t * 16 + lane15) * 32 + (quad ^ ksz) * 8];
            st[t] = __builtin_amdgcn_mfma_f32_16x16x32_bf16(aK, bQ, (f32x4){0.f, 0.f, 0.f, 0.f}, 0, 0, 0);
        }
        __builtin_amdgcn_s_setprio(0);

        // ---- softmax: bare exp2, norm deferred ----
        float sum = 0.f;
#pragma unroll
        for (int t = 0; t < 16; ++t)
#pragma unroll
            for (int r = 0; r < 4; ++r) {
                float e = __builtin_amdgcn_exp2f(st[t][r]);
                st[t][r] = e;
                sum += e;
            }
        sum += __shfl_xor(sum, 16);
        sum += __shfl_xor(sum, 32);
        const float inv = 1.f / sum;

        // ---- PV in 4 key-chunks of 64, unnormalized P through LDS ----
        f32x4 oacc[2] = {{0.f, 0.f, 0.f, 0.f}, {0.f, 0.f, 0.f, 0.f}};
        const int prow = (wv * 16 + lane15) * 72;
#pragma unroll
        for (int cc = 0; cc < 4; ++cc) {
#pragma unroll
            for (int tt = 0; tt < 4; ++tt) {
                int t = cc * 4 + tt;
                uint2 pk;
                pk.x = pk2bf(st[t][0], st[t][1]);
                pk.y = pk2bf(st[t][2], st[t][3]);
                *(uint2*)&Ps[prow + tt * 16 + quad * 4] = pk;
            }
            __builtin_amdgcn_s_setprio(1);
#pragma unroll
            for (int kt = 0; kt < 2; ++kt) {
                bf16x8 aP = *(const bf16x8*)&Ps[prow + kt * 32 + quad * 8];
#pragma unroll
                for (int nt = 0; nt < 2; ++nt) {
                    bf16x8 bV = *(const bf16x8*)&Vt[(nt * 16 + lane15) * 264 + cc * 64 + kt * 32 + quad * 8];
                    oacc[nt] = __builtin_amdgcn_mfma_f32_16x16x32_bf16(aP, bV, oacc[nt], 0, 0, 0);
                }
            }
            __builtin_amdgcn_s_setprio(0);
        }

        // ---- q' slice -> LDS (wave owns exactly its 16 rows) ----
#pragma unroll
        for (int nt = 0; nt < 2; ++nt)
#pragma unroll
            for (int r = 0; r < 4; ++r) {
                int row = wv * 16 + quad * 4 + r;
                Qp[row * 264 + h * 32 + nt * 16 + lane15] = f2bf(oacc[nt][r] * inv);
            }
    }

    // ---- output projection: wave's 16 rows x 256 cols from Qp (wave-own
    // rows: within-wave LDS ordering suffices, no barrier needed) ----
    bf16x8 aF[8];
#pragma unroll
    for (int kt = 0; kt < 8; ++kt)
        aF[kt] = *(const bf16x8*)&Qp[(wv * 16 + lane15) * 264 + kt * 32 + quad * 8];

    // un-window scatter base for this block's window
    const int wbase = nd * 3136 + (p / 7) * 8 * 56 + (p % 7) * 8;
    int xr4[4];
#pragma unroll
    for (int r = 0; r < 4; ++r) {
        int pix = wv * 16 + quad * 4 + r;
        xr4[r] = wbase + (pix >> 3) * 56 + (pix & 7);
    }

#pragma unroll
    for (int nt = 0; nt < 16; ++nt) {
        const ushort* bp = Wot + (size_t)(nt * 16 + lane15) * 256 + quad * 8;
        f32x4 acc = (f32x4){0.f, 0.f, 0.f, 0.f};
#pragma unroll
        for (int kt = 0; kt < 8; ++kt) {
            bf16x8 bF = *(const bf16x8*)(bp + kt * 32);
            acc = __builtin_amdgcn_mfma_f32_16x16x32_bf16(aF[kt], bF, acc, 0, 0, 0);
        }
        int col = nt * 16 + lane15;
        float bias = bo[col];
#pragma unroll
        for (int r = 0; r < 4; ++r)
            out[(size_t)xr4[r] * 256 + col] = acc[r] + bias;
    }
}

// ---------------------------------------------------------------------------
extern "C" void kernel_launch(void* const* d_in, const int* in_sizes, int n_in,
                              void* d_out, int out_size, void* d_ws, size_t ws_size,
                              hipStream_t stream) {
    const float* x    = (const float*)d_in[0];
    const float* Wqkv = (const float*)d_in[1];
    const float* bqkv = (const float*)d_in[2];
    const float* Wo   = (const float*)d_in[3];
    const float* bo   = (const float*)d_in[4];
    float* out = (float*)d_out;

    char* ws = (char*)d_ws;
    ushort* xg    = (ushort*)ws;                    ws += (size_t)50176 * 256 * 2;
    ushort* q     = (ushort*)ws;                    ws += (size_t)50176 * 256 * 2;
    ushort* kv    = (ushort*)ws;                    ws += (size_t)50176 * 512 * 2;
    ushort* Wqkvt = (ushort*)ws;                    ws += (size_t)768 * 256 * 2;
    ushort* Wot   = (ushort*)ws;                    ws += (size_t)256 * 256 * 2;
    float*  xmean = (float*)ws;                     ws += (size_t)784 * 256 * 4;
    float*  qwin  = (float*)ws;                     ws += (size_t)784 * 256 * 4;
    float*  kwin  = (float*)ws;                     ws += (size_t)784 * 256 * 4;
    int*    ridx  = (int*)ws;

    k_prep    <<<1808, 256, 0, stream>>>(x, Wqkv, Wo, xg, xmean, Wqkvt, Wot);
    k_winproj <<<dim3(8, 13), 256, 0, stream>>>(xmean, Wqkv, bqkv, qwin, kwin);
    k_route   <<<784, 256, 0, stream>>>(qwin, kwin, ridx);
    k_gemm_qkv<<<dim3(6, 392), 256, 0, stream>>>(xg, Wqkvt, bqkv, q, kv);
    k_attn_o  <<<784, 256, 0, stream>>>(q, kv, ridx, Wot, bo, out);
}

// Round 8
// 231.244 us; speedup vs baseline: 1.2629x; 1.2629x over previous
//
#include <hip/hip_runtime.h>
#include <hip/hip_bf16.h>
#include <math.h>

// attention scale folded with log2(e) for exp2-based softmax:
// q_attn = q * (256^-0.5 * log2(e))
#define QSC 0.09016844f

typedef __attribute__((ext_vector_type(8))) short bf16x8;
typedef __attribute__((ext_vector_type(4))) float f32x4;

// fp32 -> bf16 round-to-nearest-even
__device__ __forceinline__ ushort f2bf(float f) {
    unsigned u = __float_as_uint(f);
    return (ushort)((u + 0x7FFFu + ((u >> 16) & 1u)) >> 16);
}

__device__ __forceinline__ unsigned pk2bf(float a, float b) {
    __hip_bfloat162 h = __float22bfloat162_rn(make_float2(a, b));
    return *(unsigned*)&h;
}

// async global->LDS, 16B per lane. LDS dest must be wave-uniform base + lane*16.
__device__ __forceinline__ void gl_lds16(const ushort* g, ushort* l) {
    __builtin_amdgcn_global_load_lds(
        (const __attribute__((address_space(1))) unsigned int*)g,
        (__attribute__((address_space(3))) unsigned int*)l, 16, 0, 0);
}

// XOR swizzle for DMA-staged [row][4x8ushort] tiles: kills the 8-way
// fragment-read conflict (row stride 64B) without padding.
__device__ __forceinline__ int swz(int row) { return (row ^ (row >> 2)) & 3; }

// ---------------------------------------------------------------------------
// K1: merged prep. Blocks [0,784): window-gather cast x->xg (bf16, window
// order) + fp32 window means (one pass over x). Blocks [784,1808): weight
// transpose+cast.
// ---------------------------------------------------------------------------
__global__ __launch_bounds__(256) void k_prep(const float* __restrict__ x,
                                              const float* __restrict__ Wqkv,
                                              const float* __restrict__ Wo,
                                              ushort* __restrict__ xg,
                                              float* __restrict__ xmean,
                                              ushort* __restrict__ Wqkvt,
                                              ushort* __restrict__ Wot) {
    int b = blockIdx.x;
    int tid = threadIdx.x;
    if (b >= 784) {
        int bb = b - 784;
        if (bb < 768) Wqkvt[bb * 256 + tid] = f2bf(Wqkv[(size_t)tid * 768 + bb]);
        else { int n = bb - 768; Wot[n * 256 + tid] = f2bf(Wo[(size_t)tid * 256 + n]); }
        return;
    }
    int nd = b / 49, p = b % 49;
    int j = p / 7, i = p % 7;
    const float* xb = x + ((size_t)nd * 3136 + (j * 8) * 56 + i * 8) * 256 + tid;
    ushort* xo = xg + (size_t)b * 64 * 256 + tid;
    float s = 0.f;
#pragma unroll 2
    for (int hh = 0; hh < 8; ++hh)
#pragma unroll
        for (int ww = 0; ww < 8; ++ww) {
            float v = xb[(size_t)(hh * 56 + ww) * 256];
            s += v;
            xo[(size_t)(hh * 8 + ww) * 256] = f2bf(v);
        }
    xmean[(size_t)b * 256 + tid] = s * (1.f / 64.f);
}

// ---------------------------------------------------------------------------
// Routing projection, pure fp32 (decoupled from bf16 numerics).
// ---------------------------------------------------------------------------
__global__ __launch_bounds__(256) void k_winproj(const float* __restrict__ xmean,
                                                 const float* __restrict__ Wqkv,
                                                 const float* __restrict__ bqkv,
                                                 float* __restrict__ qwin,
                                                 float* __restrict__ kwin) {
    __shared__ float As[16 * 68];
    __shared__ float Bs[16 * 64];
    const int tid = threadIdx.x;
    const int m0 = blockIdx.y * 64;
    const int n0 = blockIdx.x * 64;

    const int ar = tid >> 2;
    const int ak = (tid & 3) * 4;
    const int arow = (m0 + ar < 784) ? (m0 + ar) : 783;
    const float* aptr = xmean + (size_t)arow * 256 + ak;

    const int bk = tid >> 4;
    const int bn = (tid & 15) * 4;
    const float* bptr = Wqkv + (size_t)bk * 768 + n0 + bn;

    const int ty = tid >> 4, tx = tid & 15;
    float acc[4][4] = {};

    for (int kt = 0; kt < 256; kt += 16) {
        float4 av = *(const float4*)(aptr + kt);
        float4 bv = *(const float4*)(bptr + (size_t)kt * 768);
        __syncthreads();
        As[(ak + 0) * 68 + ar] = av.x;
        As[(ak + 1) * 68 + ar] = av.y;
        As[(ak + 2) * 68 + ar] = av.z;
        As[(ak + 3) * 68 + ar] = av.w;
        *(float4*)&Bs[bk * 64 + bn] = bv;
        __syncthreads();
#pragma unroll
        for (int kk = 0; kk < 16; ++kk) {
            float4 a4 = *(const float4*)&As[kk * 68 + ty * 4];
            float4 b4 = *(const float4*)&Bs[kk * 64 + tx * 4];
            float a[4] = {a4.x, a4.y, a4.z, a4.w};
            float b[4] = {b4.x, b4.y, b4.z, b4.w};
#pragma unroll
            for (int ii = 0; ii < 4; ++ii)
#pragma unroll
                for (int jj = 0; jj < 4; ++jj) acc[ii][jj] += a[ii] * b[jj];
        }
    }
#pragma unroll
    for (int ii = 0; ii < 4; ++ii) {
        int t = m0 + ty * 4 + ii;
        if (t >= 784) continue;
#pragma unroll
        for (int jj = 0; jj < 4; ++jj) {
            int col = n0 + tx * 4 + jj;
            float v = acc[ii][jj] + bqkv[col];
            if (col < 256) qwin[(size_t)t * 256 + col] = v;
            else           kwin[(size_t)t * 256 + (col - 256)] = v;
        }
    }
}

// ---------------------------------------------------------------------------
// Routing top-k. 4 waves split the 256-channel dot product (float4 loads),
// LDS partial reduce, wave 0 does the top-4 selection.
// ---------------------------------------------------------------------------
__global__ __launch_bounds__(256) void k_route(const float* __restrict__ qwin,
                                               const float* __restrict__ kwin,
                                               int* __restrict__ ridx) {
    const int b = blockIdx.x;                 // nd*49 + p
    const int nd = b / 49;
    const int ndkv = ((nd & 7) == 7) ? nd : nd + 1;
    const int tid = threadIdx.x;
    const int t = tid & 63, w = tid >> 6;
    __shared__ float qs[256];
    __shared__ float part[4][64];
    qs[tid] = qwin[b * 256 + tid];
    __syncthreads();
    float s = 0.f;
    if (t < 49) {
        const float* kr = kwin + ((size_t)ndkv * 49 + t) * 256 + w * 64;
#pragma unroll
        for (int c = 0; c < 64; c += 4) {
            float4 k4 = *(const float4*)(kr + c);
            float4 q4 = *(const float4*)&qs[w * 64 + c];
            s += q4.x * k4.x + q4.y * k4.y + q4.z * k4.z + q4.w * k4.w;
        }
    }
    part[w][t] = s;
    __syncthreads();
    if (tid < 64) {
        float logit = (t < 49) ? (part[0][t] + part[1][t] + part[2][t] + part[3][t])
                               : -INFINITY;
        for (int sel = 0; sel < 4; ++sel) {
            float v = logit;
            int ix = t;
            for (int off = 32; off > 0; off >>= 1) {
                float ov = __shfl_xor(v, off);
                int   oi = __shfl_xor(ix, off);
                if (ov > v || (ov == v && oi < ix)) { v = ov; ix = oi; }
            }
            if (t == 0) ridx[b * 4 + sel] = ix;
            if (t == ix) logit = -INFINITY;
        }
    }
}

// ---------------------------------------------------------------------------
// K2: bf16 MFMA GEMM, 128x128 tile, BK=32, 2-phase double-buffered
// direct-to-LDS staging (stage t+1 while computing t; one vmcnt(0)+barrier
// per K-step). 32 KB LDS -> 5 blocks/CU: inter-block overlap is the
// latency-hider. XCD-chunked swizzle keeps the 6 N-tiles sharing an A-panel
// on one XCD L2. [proven best: R1/R3/R5 band]
// ---------------------------------------------------------------------------
__global__ __launch_bounds__(256) void k_gemm_qkv(const ushort* __restrict__ A,
                                                  const ushort* __restrict__ Bt,
                                                  const float* __restrict__ bqkv,
                                                  ushort* __restrict__ q,
                                                  ushort* __restrict__ kv) {
    __shared__ ushort As[2][128 * 32];
    __shared__ ushort Bs[2][128 * 32];
    const int tid = threadIdx.x;
    const int wv = tid >> 6, ln = tid & 63;
    const int lane15 = ln & 15, quad = ln >> 4;

    // bijective XCD swizzle: nwg = 2352 = 8 * 294.
    const int lin  = blockIdx.x + blockIdx.y * 6;
    const int work = (lin & 7) * 294 + (lin >> 3);
    const int n0 = (work % 6) * 128;
    const int m0 = (work / 6) * 128;

    const int row0 = tid >> 2, ck0 = tid & 3;
    const ushort* gA[2]; const ushort* gB[2];
    int lofs[2];
#pragma unroll
    for (int p = 0; p < 2; ++p) {
        int r = p * 64 + row0;
        int cks = ck0 ^ swz(r);               // swizzled chunk this lane stages
        gA[p] = A  + (size_t)(m0 + r) * 256 + cks * 8;
        gB[p] = Bt + (size_t)(n0 + r) * 256 + cks * 8;
        lofs[p] = (p * 256 + tid) * 8;
    }

    f32x4 acc[4][4];
#pragma unroll
    for (int i = 0; i < 4; ++i)
#pragma unroll
        for (int j = 0; j < 4; ++j) acc[i][j] = (f32x4){0.f, 0.f, 0.f, 0.f};

    const int mb = (wv >> 1) * 64, nb = (wv & 1) * 64;

    // prologue: stage K-tile 0 into buf 0
#pragma unroll
    for (int p = 0; p < 2; ++p) {
        gl_lds16(gA[p], &As[0][lofs[p]]);
        gl_lds16(gB[p], &Bs[0][lofs[p]]);
    }
    asm volatile("s_waitcnt vmcnt(0)" ::: "memory");
    __builtin_amdgcn_s_barrier();

    int cur = 0;
#pragma unroll
    for (int kt = 0; kt < 8; ++kt) {
        if (kt < 7) {                          // issue next tile's loads first
#pragma unroll
            for (int p = 0; p < 2; ++p) {
                gl_lds16(gA[p] + (kt + 1) * 32, &As[cur ^ 1][lofs[p]]);
                gl_lds16(gB[p] + (kt + 1) * 32, &Bs[cur ^ 1][lofs[p]]);
            }
        }
        __builtin_amdgcn_sched_barrier(0);
        bf16x8 aF[4], bF[4];
#pragma unroll
        for (int mt = 0; mt < 4; ++mt) {
            int r = mb + mt * 16 + lane15;
            aF[mt] = *(const bf16x8*)&As[cur][r * 32 + (quad ^ swz(r)) * 8];
        }
#pragma unroll
        for (int nt = 0; nt < 4; ++nt) {
            int r = nb + nt * 16 + lane15;
            bF[nt] = *(const bf16x8*)&Bs[cur][r * 32 + (quad ^ swz(r)) * 8];
        }
#pragma unroll
        for (int mt = 0; mt < 4; ++mt)
#pragma unroll
            for (int nt = 0; nt < 4; ++nt)
                acc[mt][nt] = __builtin_amdgcn_mfma_f32_16x16x32_bf16(aF[mt], bF[nt], acc[mt][nt], 0, 0, 0);
        __builtin_amdgcn_sched_barrier(0);
        asm volatile("s_waitcnt vmcnt(0)" ::: "memory");   // next tile landed
        __builtin_amdgcn_s_barrier();                      // all waves done reading cur
        cur ^= 1;
    }

#pragma unroll
    for (int mt = 0; mt < 4; ++mt) {
#pragma unroll
        for (int nt = 0; nt < 4; ++nt) {
            int col = n0 + nb + nt * 16 + lane15;
            float bias = bqkv[col];
#pragma unroll
            for (int r = 0; r < 4; ++r) {
                int t = m0 + mb + mt * 16 + quad * 4 + r;
                float v = acc[mt][nt][r] + bias;
                if (col < 256) q[(size_t)t * 256 + col] = f2bf(v * QSC);
                else           kv[(size_t)t * 512 + (col - 256)] = f2bf(v);
            }
        }
    }
}

// ---------------------------------------------------------------------------
// K4: output projection GEMM (same 2-phase pipeline) + wave-uniform
// un-window scatter, fp32 out.
// ---------------------------------------------------------------------------
__global__ __launch_bounds__(256) void k_gemm_o(const ushort* __restrict__ A,
                                                const ushort* __restrict__ Bt,
                                                const float* __restrict__ bo,
                                                float* __restrict__ out) {
    __shared__ ushort As[2][128 * 32];
    __shared__ ushort Bs[2][128 * 32];
    const int tid = threadIdx.x;
    const int wv = tid >> 6, ln = tid & 63;
    const int lane15 = ln & 15, quad = ln >> 4;

    // nwg = 784 = 8 * 98.
    const int lin  = blockIdx.x;
    const int work = (lin & 7) * 98 + (lin >> 3);
    const int n0 = (work % 2) * 128;
    const int m0 = (work / 2) * 128;

    const int row0 = tid >> 2, ck0 = tid & 3;
    const ushort* gA[2]; const ushort* gB[2];
    int lofs[2];
#pragma unroll
    for (int p = 0; p < 2; ++p) {
        int r = p * 64 + row0;
        int cks = ck0 ^ swz(r);
        gA[p] = A  + (size_t)(m0 + r) * 256 + cks * 8;
        gB[p] = Bt + (size_t)(n0 + r) * 256 + cks * 8;
        lofs[p] = (p * 256 + tid) * 8;
    }

    f32x4 acc[4][4];
#pragma unroll
    for (int i = 0; i < 4; ++i)
#pragma unroll
        for (int j = 0; j < 4; ++j) acc[i][j] = (f32x4){0.f, 0.f, 0.f, 0.f};

    const int mb = (wv >> 1) * 64, nb = (wv & 1) * 64;

#pragma unroll
    for (int p = 0; p < 2; ++p) {
        gl_lds16(gA[p], &As[0][lofs[p]]);
        gl_lds16(gB[p], &Bs[0][lofs[p]]);
    }
    asm volatile("s_waitcnt vmcnt(0)" ::: "memory");
    __builtin_amdgcn_s_barrier();

    int cur = 0;
#pragma unroll
    for (int kt = 0; kt < 8; ++kt) {
        if (kt < 7) {
#pragma unroll
            for (int p = 0; p < 2; ++p) {
                gl_lds16(gA[p] + (kt + 1) * 32, &As[cur ^ 1][lofs[p]]);
                gl_lds16(gB[p] + (kt + 1) * 32, &Bs[cur ^ 1][lofs[p]]);
            }
        }
        __builtin_amdgcn_sched_barrier(0);
        bf16x8 aF[4], bF[4];
#pragma unroll
        for (int mt = 0; mt < 4; ++mt) {
            int r = mb + mt * 16 + lane15;
            aF[mt] = *(const bf16x8*)&As[cur][r * 32 + (quad ^ swz(r)) * 8];
        }
#pragma unroll
        for (int nt = 0; nt < 4; ++nt) {
            int r = nb + nt * 16 + lane15;
            bF[nt] = *(const bf16x8*)&Bs[cur][r * 32 + (quad ^ swz(r)) * 8];
        }
#pragma unroll
        for (int mt = 0; mt < 4; ++mt)
#pragma unroll
            for (int nt = 0; nt < 4; ++nt)
                acc[mt][nt] = __builtin_amdgcn_mfma_f32_16x16x32_bf16(aF[mt], bF[nt], acc[mt][nt], 0, 0, 0);
        __builtin_amdgcn_sched_barrier(0);
        asm volatile("s_waitcnt vmcnt(0)" ::: "memory");
        __builtin_amdgcn_s_barrier();
        cur ^= 1;
    }

    // epilogue: wave's 64 rows = exactly one window -> cheap un-window scatter
    const int w6 = (m0 + mb) >> 6;               // window-linear index
    const int ndw = w6 / 49, pw = w6 % 49;
    const int wbase = ndw * 3136 + (pw / 7) * 8 * 56 + (pw % 7) * 8;
#pragma unroll
    for (int mt = 0; mt < 4; ++mt)
#pragma unroll
        for (int nt = 0; nt < 4; ++nt) {
            int col = n0 + nb + nt * 16 + lane15;
            float bias = bo[col];
#pragma unroll
            for (int r = 0; r < 4; ++r) {
                int pix = mt * 16 + quad * 4 + r;
                int xr = wbase + (pix >> 3) * 56 + (pix & 7);
                out[(size_t)xr * 256 + col] = acc[mt][nt][r] + bias;
            }
        }
}

// ---------------------------------------------------------------------------
// K3: attention per (head, window, nd). q already carries SCALE*log2e:
// softmax = exp2(score), normalization deferred to the output store.
// K staged via global_load_lds into linear [key][32ch] with XOR-chunk
// swizzle (LDS slot (key,c) holds global chunk c ^ swz(key); lane ln's
// source chunk is (ln ^ (ln>>2) ^ (ln>>4)) & 3).
// OCCUPANCY FIX: Ps (9 KB) aliases Ks (16 KB) — Ks is dead after QK^T; a
// barrier separates the last Ks read from the first Ps write. LDS footprint
// 41.5 -> 32.5 KB => 4 blocks/CU (was 3), +33% resident waves for this
// latency-bound kernel. __launch_bounds__(256,4) pins VGPR <= 128.
// XCD swizzle groups all 8 heads of one (p,nd) on one XCD (kv L2 reuse).
// s_setprio(1) around MFMA clusters (T5).
// ---------------------------------------------------------------------------
__global__ __launch_bounds__(256, 4) void k_attn(ushort* qbuf,
                                                 const ushort* __restrict__ kvbuf,
                                                 const int* __restrict__ ridx) {
    // nwg = 6272 = 8 * 784; chunk = 98 (p,nd) groups x 8 heads per XCD.
    const int lin  = blockIdx.x + (blockIdx.y + blockIdx.z * 49) * 8;
    const int work = (lin & 7) * 784 + (lin >> 3);
    const int h = work & 7;
    const int rest = work >> 3;
    const int p = rest % 49;
    const int nd = rest / 49;

    const int ndkv = ((nd & 7) == 7) ? nd : nd + 1;
    const int tid = threadIdx.x;
    const int wv = tid >> 6, ln = tid & 63;
    const int lane15 = ln & 15, quad = ln >> 4;

    __shared__ ushort Ks[256 * 32];   // [key][32ch]; first 9 KB reused as Ps
    __shared__ ushort Vt[32 * 264];   // [ch][key] stride 264: 16.5 KB
    ushort* Ps = Ks;                  // alias: Ks dead after QK^T (barrier'd)

    const int rb = (nd * 49 + p) * 4;
    int wid[4];
#pragma unroll
    for (int i = 0; i < 4; ++i) wid[i] = ridx[rb + i];

    const size_t kvband = (size_t)ndkv * 49;

    // ---- stage K via DMA: dest linear (base + ln*16B), source pre-swizzled.
    {
        const int key_l = wv * 16 + (ln >> 2);             // key within window
        const int ck = (ln ^ (ln >> 2) ^ (ln >> 4)) & 3;   // (ln&3) ^ swz(key_l)
#pragma unroll
        for (int i = 0; i < 4; ++i) {
            size_t trow = (kvband + wid[i]) * 64 + key_l;
            gl_lds16(kvbuf + trow * 512 + h * 32 + ck * 8,
                     &Ks[(i * 64 + wv * 16) * 32 + ln * 8]);
        }
    }

    // ---- Q B-frag from global (wave's own 16 q-rows): issue before the
    // VALU-heavy V staging so its latency hides under that work.
    const size_t qrow0 = (size_t)(nd * 49 + p) * 64;
    bf16x8 bQ = *(const bf16x8*)(qbuf + (qrow0 + wv * 16 + lane15) * 256 + h * 32 + quad * 8);

    // ---- stage V transposed: Vt[ch][key] ----
    {
        int key_l = (tid & 31) * 2;       // 0..62 within window
        int ch0 = (tid >> 5) * 4;         // 0..28
#pragma unroll
        for (int i = 0; i < 4; ++i) {
            size_t trow = (kvband + wid[i]) * 64;
            const ushort* g0 = kvbuf + (trow + key_l) * 512 + 256 + h * 32 + ch0;
            const ushort* g1 = g0 + 512;
            ushort4 a = *(const ushort4*)g0;
            ushort4 b = *(const ushort4*)g1;
            int kg = i * 64 + key_l;
            *(unsigned*)&Vt[(ch0 + 0) * 264 + kg] = (unsigned)a.x | ((unsigned)b.x << 16);
            *(unsigned*)&Vt[(ch0 + 1) * 264 + kg] = (unsigned)a.y | ((unsigned)b.y << 16);
            *(unsigned*)&Vt[(ch0 + 2) * 264 + kg] = (unsigned)a.z | ((unsigned)b.z << 16);
            *(unsigned*)&Vt[(ch0 + 3) * 264 + kg] = (unsigned)a.w | ((unsigned)b.w << 16);
        }
    }

    __syncthreads();   // drains vmcnt (K-DMA) + lgkmcnt (V writes)

    // ---- S^T = K · Q^T ; frag read undoes the chunk swizzle:
    // swz(t*16+lane15) == (lane15 ^ (lane15>>2)) & 3 (per-lane constant).
    const int ksz = (lane15 ^ (lane15 >> 2)) & 3;
    f32x4 st[16];
    __builtin_amdgcn_s_setprio(1);
#pragma unroll
    for (int t = 0; t < 16; ++t) {
        bf16x8 aK = *(const bf16x8*)&Ks[(t * 16 + lane15) * 32 + (quad ^ ksz) * 8];
        st[t] = __builtin_amdgcn_mfma_f32_16x16x32_bf16(aK, bQ, (f32x4){0.f, 0.f, 0.f, 0.f}, 0, 0, 0);
    }
    __builtin_amdgcn_s_setprio(0);

    __syncthreads();   // ALL waves done reading Ks -> safe to reuse as Ps

    // ---- softmax: bare exp2 (v_exp_f32), no max, norm deferred ----
    float sum = 0.f;
#pragma unroll
    for (int t = 0; t < 16; ++t)
#pragma unroll
        for (int r = 0; r < 4; ++r) {
            float e = __builtin_amdgcn_exp2f(st[t][r]);
            st[t][r] = e;
            sum += e;
        }
    sum += __shfl_xor(sum, 16);
    sum += __shfl_xor(sum, 32);
    const float inv = 1.f / sum;

    // ---- PV in 4 key-chunks of 64, unnormalized P through LDS (aliased) ----
    f32x4 oacc[2] = {{0.f, 0.f, 0.f, 0.f}, {0.f, 0.f, 0.f, 0.f}};
    const int prow = (wv * 16 + lane15) * 72;
#pragma unroll
    for (int cc = 0; cc < 4; ++cc) {
#pragma unroll
        for (int tt = 0; tt < 4; ++tt) {
            int t = cc * 4 + tt;
            uint2 pk;
            pk.x = pk2bf(st[t][0], st[t][1]);
            pk.y = pk2bf(st[t][2], st[t][3]);
            *(uint2*)&Ps[prow + tt * 16 + quad * 4] = pk;
        }
        __builtin_amdgcn_s_setprio(1);
#pragma unroll
        for (int kt = 0; kt < 2; ++kt) {
            bf16x8 aP = *(const bf16x8*)&Ps[prow + kt * 32 + quad * 8];
#pragma unroll
            for (int nt = 0; nt < 2; ++nt) {
                bf16x8 bV = *(const bf16x8*)&Vt[(nt * 16 + lane15) * 264 + cc * 64 + kt * 32 + quad * 8];
                oacc[nt] = __builtin_amdgcn_mfma_f32_16x16x32_bf16(aP, bV, oacc[nt], 0, 0, 0);
            }
        }
        __builtin_amdgcn_s_setprio(0);
    }

    // ---- store (in-place over qbuf; wave owns exactly its 16 rows) ----
#pragma unroll
    for (int nt = 0; nt < 2; ++nt)
#pragma unroll
        for (int r = 0; r < 4; ++r) {
            int row = wv * 16 + quad * 4 + r;
            qbuf[(qrow0 + row) * 256 + h * 32 + nt * 16 + lane15] = f2bf(oacc[nt][r] * inv);
        }
}

// ---------------------------------------------------------------------------
extern "C" void kernel_launch(void* const* d_in, const int* in_sizes, int n_in,
                              void* d_out, int out_size, void* d_ws, size_t ws_size,
                              hipStream_t stream) {
    const float* x    = (const float*)d_in[0];
    const float* Wqkv = (const float*)d_in[1];
    const float* bqkv = (const float*)d_in[2];
    const float* Wo   = (const float*)d_in[3];
    const float* bo   = (const float*)d_in[4];
    float* out = (float*)d_out;

    char* ws = (char*)d_ws;
    ushort* xg    = (ushort*)ws;                    ws += (size_t)50176 * 256 * 2;
    ushort* q     = (ushort*)ws;                    ws += (size_t)50176 * 256 * 2;
    ushort* kv    = (ushort*)ws;                    ws += (size_t)50176 * 512 * 2;
    ushort* Wqkvt = (ushort*)ws;                    ws += (size_t)768 * 256 * 2;
    ushort* Wot   = (ushort*)ws;                    ws += (size_t)256 * 256 * 2;
    float*  xmean = (float*)ws;                     ws += (size_t)784 * 256 * 4;
    float*  qwin  = (float*)ws;                     ws += (size_t)784 * 256 * 4;
    float*  kwin  = (float*)ws;                     ws += (size_t)784 * 256 * 4;
    int*    ridx  = (int*)ws;

    k_prep    <<<1808, 256, 0, stream>>>(x, Wqkv, Wo, xg, xmean, Wqkvt, Wot);
    k_winproj <<<dim3(8, 13), 256, 0, stream>>>(xmean, Wqkv, bqkv, qwin, kwin);
    k_route   <<<784, 256, 0, stream>>>(qwin, kwin, ridx);
    k_gemm_qkv<<<dim3(6, 392), 256, 0, stream>>>(xg, Wqkvt, bqkv, q, kv);
    k_attn    <<<dim3(8, 49, 16), 256, 0, stream>>>(q, kv, ridx);
    k_gemm_o  <<<784, 256, 0, stream>>>(q, Wot, bo, out);
}

// Round 9
// 224.968 us; speedup vs baseline: 1.2981x; 1.0279x over previous
//
#include <hip/hip_runtime.h>
#include <hip/hip_bf16.h>
#include <math.h>

// attention scale folded with log2(e) for exp2-based softmax:
// q_attn = q * (256^-0.5 * log2(e))
#define QSC 0.09016844f

typedef __attribute__((ext_vector_type(8))) short bf16x8;
typedef __attribute__((ext_vector_type(4))) float f32x4;

// fp32 -> bf16 round-to-nearest-even
__device__ __forceinline__ ushort f2bf(float f) {
    unsigned u = __float_as_uint(f);
    return (ushort)((u + 0x7FFFu + ((u >> 16) & 1u)) >> 16);
}

__device__ __forceinline__ unsigned pk2bf(float a, float b) {
    __hip_bfloat162 h = __float22bfloat162_rn(make_float2(a, b));
    return *(unsigned*)&h;
}

// async global->LDS, 16B per lane. LDS dest must be wave-uniform base + lane*16.
__device__ __forceinline__ void gl_lds16(const ushort* g, ushort* l) {
    __builtin_amdgcn_global_load_lds(
        (const __attribute__((address_space(1))) unsigned int*)g,
        (__attribute__((address_space(3))) unsigned int*)l, 16, 0, 0);
}

// XOR swizzle for DMA-staged [row][4x8ushort] tiles: kills the 8-way
// fragment-read conflict (row stride 64B) without padding.
__device__ __forceinline__ int swz(int row) { return (row ^ (row >> 2)) & 3; }

// ---------------------------------------------------------------------------
// K1: merged prep. Blocks [0,784): window-gather cast x->xg (bf16, window
// order) + fp32 window means, VECTORIZED: thread = (pixel-group pg of 16,
// channel-group cg of 4); float4 loads (1 KB/wave-instr), cvt_pk + uint2
// stores, LDS partial-sum reduce for the mean. 4x fewer memory instructions
// than the scalar version. Blocks [784,1808): weight transpose+cast.
// ---------------------------------------------------------------------------
__global__ __launch_bounds__(256) void k_prep(const float* __restrict__ x,
                                              const float* __restrict__ Wqkv,
                                              const float* __restrict__ Wo,
                                              ushort* __restrict__ xg,
                                              float* __restrict__ xmean,
                                              ushort* __restrict__ Wqkvt,
                                              ushort* __restrict__ Wot) {
    int b = blockIdx.x;
    int tid = threadIdx.x;
    if (b >= 784) {
        int bb = b - 784;
        if (bb < 768) Wqkvt[bb * 256 + tid] = f2bf(Wqkv[(size_t)tid * 768 + bb]);
        else { int n = bb - 768; Wot[n * 256 + tid] = f2bf(Wo[(size_t)tid * 256 + n]); }
        return;
    }
    int nd = b / 49, p = b % 49;
    int j = p / 7, i = p % 7;
    const int cg = tid & 63;          // 4 consecutive channels: cg*4..cg*4+3
    const int pg = tid >> 6;          // 16 pixels = 2 window rows: pg*2, pg*2+1

    const float* xb = x + ((size_t)nd * 3136 + ((size_t)(j * 8 + pg * 2)) * 56 + i * 8) * 256 + cg * 4;
    ushort* xo = xg + (size_t)b * 64 * 256 + (size_t)pg * 16 * 256 + cg * 4;

    __shared__ float4 part[4][64];
    float4 s = make_float4(0.f, 0.f, 0.f, 0.f);
#pragma unroll
    for (int r = 0; r < 2; ++r)
#pragma unroll
        for (int w = 0; w < 8; ++w) {
            float4 v = *(const float4*)(xb + (size_t)(r * 56 + w) * 256);
            s.x += v.x; s.y += v.y; s.z += v.z; s.w += v.w;
            uint2 pk;
            pk.x = pk2bf(v.x, v.y);
            pk.y = pk2bf(v.z, v.w);
            *(uint2*)(xo + (size_t)(r * 8 + w) * 256) = pk;
        }
    part[pg][cg] = s;
    __syncthreads();
    if (tid < 64) {
        float4 a = part[0][tid], b4 = part[1][tid], c = part[2][tid], d = part[3][tid];
        float4 m;
        m.x = (a.x + b4.x + c.x + d.x) * (1.f / 64.f);
        m.y = (a.y + b4.y + c.y + d.y) * (1.f / 64.f);
        m.z = (a.z + b4.z + c.z + d.z) * (1.f / 64.f);
        m.w = (a.w + b4.w + c.w + d.w) * (1.f / 64.f);
        *(float4*)(xmean + (size_t)b * 256 + tid * 4) = m;
    }
}

// ---------------------------------------------------------------------------
// Routing projection, pure fp32 (decoupled from bf16 numerics).
// ---------------------------------------------------------------------------
__global__ __launch_bounds__(256) void k_winproj(const float* __restrict__ xmean,
                                                 const float* __restrict__ Wqkv,
                                                 const float* __restrict__ bqkv,
                                                 float* __restrict__ qwin,
                                                 float* __restrict__ kwin) {
    __shared__ float As[16 * 68];
    __shared__ float Bs[16 * 64];
    const int tid = threadIdx.x;
    const int m0 = blockIdx.y * 64;
    const int n0 = blockIdx.x * 64;

    const int ar = tid >> 2;
    const int ak = (tid & 3) * 4;
    const int arow = (m0 + ar < 784) ? (m0 + ar) : 783;
    const float* aptr = xmean + (size_t)arow * 256 + ak;

    const int bk = tid >> 4;
    const int bn = (tid & 15) * 4;
    const float* bptr = Wqkv + (size_t)bk * 768 + n0 + bn;

    const int ty = tid >> 4, tx = tid & 15;
    float acc[4][4] = {};

    for (int kt = 0; kt < 256; kt += 16) {
        float4 av = *(const float4*)(aptr + kt);
        float4 bv = *(const float4*)(bptr + (size_t)kt * 768);
        __syncthreads();
        As[(ak + 0) * 68 + ar] = av.x;
        As[(ak + 1) * 68 + ar] = av.y;
        As[(ak + 2) * 68 + ar] = av.z;
        As[(ak + 3) * 68 + ar] = av.w;
        *(float4*)&Bs[bk * 64 + bn] = bv;
        __syncthreads();
#pragma unroll
        for (int kk = 0; kk < 16; ++kk) {
            float4 a4 = *(const float4*)&As[kk * 68 + ty * 4];
            float4 b4 = *(const float4*)&Bs[kk * 64 + tx * 4];
            float a[4] = {a4.x, a4.y, a4.z, a4.w};
            float b[4] = {b4.x, b4.y, b4.z, b4.w};
#pragma unroll
            for (int ii = 0; ii < 4; ++ii)
#pragma unroll
                for (int jj = 0; jj < 4; ++jj) acc[ii][jj] += a[ii] * b[jj];
        }
    }
#pragma unroll
    for (int ii = 0; ii < 4; ++ii) {
        int t = m0 + ty * 4 + ii;
        if (t >= 784) continue;
#pragma unroll
        for (int jj = 0; jj < 4; ++jj) {
            int col = n0 + tx * 4 + jj;
            float v = acc[ii][jj] + bqkv[col];
            if (col < 256) qwin[(size_t)t * 256 + col] = v;
            else           kwin[(size_t)t * 256 + (col - 256)] = v;
        }
    }
}

// ---------------------------------------------------------------------------
// Routing top-k. 4 waves split the 256-channel dot product (float4 loads),
// LDS partial reduce, wave 0 does the top-4 selection.
// ---------------------------------------------------------------------------
__global__ __launch_bounds__(256) void k_route(const float* __restrict__ qwin,
                                               const float* __restrict__ kwin,
                                               int* __restrict__ ridx) {
    const int b = blockIdx.x;                 // nd*49 + p
    const int nd = b / 49;
    const int ndkv = ((nd & 7) == 7) ? nd : nd + 1;
    const int tid = threadIdx.x;
    const int t = tid & 63, w = tid >> 6;
    __shared__ float qs[256];
    __shared__ float part[4][64];
    qs[tid] = qwin[b * 256 + tid];
    __syncthreads();
    float s = 0.f;
    if (t < 49) {
        const float* kr = kwin + ((size_t)ndkv * 49 + t) * 256 + w * 64;
#pragma unroll
        for (int c = 0; c < 64; c += 4) {
            float4 k4 = *(const float4*)(kr + c);
            float4 q4 = *(const float4*)&qs[w * 64 + c];
            s += q4.x * k4.x + q4.y * k4.y + q4.z * k4.z + q4.w * k4.w;
        }
    }
    part[w][t] = s;
    __syncthreads();
    if (tid < 64) {
        float logit = (t < 49) ? (part[0][t] + part[1][t] + part[2][t] + part[3][t])
                               : -INFINITY;
        for (int sel = 0; sel < 4; ++sel) {
            float v = logit;
            int ix = t;
            for (int off = 32; off > 0; off >>= 1) {
                float ov = __shfl_xor(v, off);
                int   oi = __shfl_xor(ix, off);
                if (ov > v || (ov == v && oi < ix)) { v = ov; ix = oi; }
            }
            if (t == 0) ridx[b * 4 + sel] = ix;
            if (t == ix) logit = -INFINITY;
        }
    }
}

// ---------------------------------------------------------------------------
// K2: bf16 MFMA GEMM, 128x128 tile, BK=32, 2-phase double-buffered
// direct-to-LDS staging (stage t+1 while computing t; one vmcnt(0)+barrier
// per K-step). 32 KB LDS -> 5 blocks/CU: inter-block overlap is the
// latency-hider. XCD-chunked swizzle keeps the 6 N-tiles sharing an A-panel
// on one XCD L2. [proven best: R1/R3/R5/R8 band]
// ---------------------------------------------------------------------------
__global__ __launch_bounds__(256) void k_gemm_qkv(const ushort* __restrict__ A,
                                                  const ushort* __restrict__ Bt,
                                                  const float* __restrict__ bqkv,
                                                  ushort* __restrict__ q,
                                                  ushort* __restrict__ kv) {
    __shared__ ushort As[2][128 * 32];
    __shared__ ushort Bs[2][128 * 32];
    const int tid = threadIdx.x;
    const int wv = tid >> 6, ln = tid & 63;
    const int lane15 = ln & 15, quad = ln >> 4;

    // bijective XCD swizzle: nwg = 2352 = 8 * 294.
    const int lin  = blockIdx.x + blockIdx.y * 6;
    const int work = (lin & 7) * 294 + (lin >> 3);
    const int n0 = (work % 6) * 128;
    const int m0 = (work / 6) * 128;

    const int row0 = tid >> 2, ck0 = tid & 3;
    const ushort* gA[2]; const ushort* gB[2];
    int lofs[2];
#pragma unroll
    for (int p = 0; p < 2; ++p) {
        int r = p * 64 + row0;
        int cks = ck0 ^ swz(r);               // swizzled chunk this lane stages
        gA[p] = A  + (size_t)(m0 + r) * 256 + cks * 8;
        gB[p] = Bt + (size_t)(n0 + r) * 256 + cks * 8;
        lofs[p] = (p * 256 + tid) * 8;
    }

    f32x4 acc[4][4];
#pragma unroll
    for (int i = 0; i < 4; ++i)
#pragma unroll
        for (int j = 0; j < 4; ++j) acc[i][j] = (f32x4){0.f, 0.f, 0.f, 0.f};

    const int mb = (wv >> 1) * 64, nb = (wv & 1) * 64;

    // prologue: stage K-tile 0 into buf 0
#pragma unroll
    for (int p = 0; p < 2; ++p) {
        gl_lds16(gA[p], &As[0][lofs[p]]);
        gl_lds16(gB[p], &Bs[0][lofs[p]]);
    }
    asm volatile("s_waitcnt vmcnt(0)" ::: "memory");
    __builtin_amdgcn_s_barrier();

    int cur = 0;
#pragma unroll
    for (int kt = 0; kt < 8; ++kt) {
        if (kt < 7) {                          // issue next tile's loads first
#pragma unroll
            for (int p = 0; p < 2; ++p) {
                gl_lds16(gA[p] + (kt + 1) * 32, &As[cur ^ 1][lofs[p]]);
                gl_lds16(gB[p] + (kt + 1) * 32, &Bs[cur ^ 1][lofs[p]]);
            }
        }
        __builtin_amdgcn_sched_barrier(0);
        bf16x8 aF[4], bF[4];
#pragma unroll
        for (int mt = 0; mt < 4; ++mt) {
            int r = mb + mt * 16 + lane15;
            aF[mt] = *(const bf16x8*)&As[cur][r * 32 + (quad ^ swz(r)) * 8];
        }
#pragma unroll
        for (int nt = 0; nt < 4; ++nt) {
            int r = nb + nt * 16 + lane15;
            bF[nt] = *(const bf16x8*)&Bs[cur][r * 32 + (quad ^ swz(r)) * 8];
        }
#pragma unroll
        for (int mt = 0; mt < 4; ++mt)
#pragma unroll
            for (int nt = 0; nt < 4; ++nt)
                acc[mt][nt] = __builtin_amdgcn_mfma_f32_16x16x32_bf16(aF[mt], bF[nt], acc[mt][nt], 0, 0, 0);
        __builtin_amdgcn_sched_barrier(0);
        asm volatile("s_waitcnt vmcnt(0)" ::: "memory");   // next tile landed
        __builtin_amdgcn_s_barrier();                      // all waves done reading cur
        cur ^= 1;
    }

#pragma unroll
    for (int mt = 0; mt < 4; ++mt) {
#pragma unroll
        for (int nt = 0; nt < 4; ++nt) {
            int col = n0 + nb + nt * 16 + lane15;
            float bias = bqkv[col];
#pragma unroll
            for (int r = 0; r < 4; ++r) {
                int t = m0 + mb + mt * 16 + quad * 4 + r;
                float v = acc[mt][nt][r] + bias;
                if (col < 256) q[(size_t)t * 256 + col] = f2bf(v * QSC);
                else           kv[(size_t)t * 512 + (col - 256)] = f2bf(v);
            }
        }
    }
}

// ---------------------------------------------------------------------------
// K4: output projection GEMM (same 2-phase pipeline) + wave-uniform
// un-window scatter, fp32 out.
// ---------------------------------------------------------------------------
__global__ __launch_bounds__(256) void k_gemm_o(const ushort* __restrict__ A,
                                                const ushort* __restrict__ Bt,
                                                const float* __restrict__ bo,
                                                float* __restrict__ out) {
    __shared__ ushort As[2][128 * 32];
    __shared__ ushort Bs[2][128 * 32];
    const int tid = threadIdx.x;
    const int wv = tid >> 6, ln = tid & 63;
    const int lane15 = ln & 15, quad = ln >> 4;

    // nwg = 784 = 8 * 98.
    const int lin  = blockIdx.x;
    const int work = (lin & 7) * 98 + (lin >> 3);
    const int n0 = (work % 2) * 128;
    const int m0 = (work / 2) * 128;

    const int row0 = tid >> 2, ck0 = tid & 3;
    const ushort* gA[2]; const ushort* gB[2];
    int lofs[2];
#pragma unroll
    for (int p = 0; p < 2; ++p) {
        int r = p * 64 + row0;
        int cks = ck0 ^ swz(r);
        gA[p] = A  + (size_t)(m0 + r) * 256 + cks * 8;
        gB[p] = Bt + (size_t)(n0 + r) * 256 + cks * 8;
        lofs[p] = (p * 256 + tid) * 8;
    }

    f32x4 acc[4][4];
#pragma unroll
    for (int i = 0; i < 4; ++i)
#pragma unroll
        for (int j = 0; j < 4; ++j) acc[i][j] = (f32x4){0.f, 0.f, 0.f, 0.f};

    const int mb = (wv >> 1) * 64, nb = (wv & 1) * 64;

#pragma unroll
    for (int p = 0; p < 2; ++p) {
        gl_lds16(gA[p], &As[0][lofs[p]]);
        gl_lds16(gB[p], &Bs[0][lofs[p]]);
    }
    asm volatile("s_waitcnt vmcnt(0)" ::: "memory");
    __builtin_amdgcn_s_barrier();

    int cur = 0;
#pragma unroll
    for (int kt = 0; kt < 8; ++kt) {
        if (kt < 7) {
#pragma unroll
            for (int p = 0; p < 2; ++p) {
                gl_lds16(gA[p] + (kt + 1) * 32, &As[cur ^ 1][lofs[p]]);
                gl_lds16(gB[p] + (kt + 1) * 32, &Bs[cur ^ 1][lofs[p]]);
            }
        }
        __builtin_amdgcn_sched_barrier(0);
        bf16x8 aF[4], bF[4];
#pragma unroll
        for (int mt = 0; mt < 4; ++mt) {
            int r = mb + mt * 16 + lane15;
            aF[mt] = *(const bf16x8*)&As[cur][r * 32 + (quad ^ swz(r)) * 8];
        }
#pragma unroll
        for (int nt = 0; nt < 4; ++nt) {
            int r = nb + nt * 16 + lane15;
            bF[nt] = *(const bf16x8*)&Bs[cur][r * 32 + (quad ^ swz(r)) * 8];
        }
#pragma unroll
        for (int mt = 0; mt < 4; ++mt)
#pragma unroll
            for (int nt = 0; nt < 4; ++nt)
                acc[mt][nt] = __builtin_amdgcn_mfma_f32_16x16x32_bf16(aF[mt], bF[nt], acc[mt][nt], 0, 0, 0);
        __builtin_amdgcn_sched_barrier(0);
        asm volatile("s_waitcnt vmcnt(0)" ::: "memory");
        __builtin_amdgcn_s_barrier();
        cur ^= 1;
    }

    // epilogue: wave's 64 rows = exactly one window -> cheap un-window scatter
    const int w6 = (m0 + mb) >> 6;               // window-linear index
    const int ndw = w6 / 49, pw = w6 % 49;
    const int wbase = ndw * 3136 + (pw / 7) * 8 * 56 + (pw % 7) * 8;
#pragma unroll
    for (int mt = 0; mt < 4; ++mt)
#pragma unroll
        for (int nt = 0; nt < 4; ++nt) {
            int col = n0 + nb + nt * 16 + lane15;
            float bias = bo[col];
#pragma unroll
            for (int r = 0; r < 4; ++r) {
                int pix = mt * 16 + quad * 4 + r;
                int xr = wbase + (pix >> 3) * 56 + (pix & 7);
                out[(size_t)xr * 256 + col] = acc[mt][nt][r] + bias;
            }
        }
}

// ---------------------------------------------------------------------------
// K3: attention per (head, window, nd). q already carries SCALE*log2e:
// softmax = exp2(score), normalization deferred to the output store.
// K staged via global_load_lds into linear [key][32ch] with XOR-chunk
// swizzle (LDS slot (key,c) holds global chunk c ^ swz(key); lane ln's
// source chunk is (ln ^ (ln>>2) ^ (ln>>4)) & 3).
// Ps (9 KB) aliases Ks (16 KB) — Ks dead after QK^T (barrier'd). LDS 32.5 KB
// => 4 blocks/CU. __launch_bounds__(256,4) pins VGPR <= 128.
// XCD swizzle groups all 8 heads of one (p,nd) on one XCD (kv L2 reuse).
// s_setprio(1) around MFMA clusters (T5).
// ---------------------------------------------------------------------------
__global__ __launch_bounds__(256, 4) void k_attn(ushort* qbuf,
                                                 const ushort* __restrict__ kvbuf,
                                                 const int* __restrict__ ridx) {
    // nwg = 6272 = 8 * 784; chunk = 98 (p,nd) groups x 8 heads per XCD.
    const int lin  = blockIdx.x + (blockIdx.y + blockIdx.z * 49) * 8;
    const int work = (lin & 7) * 784 + (lin >> 3);
    const int h = work & 7;
    const int rest = work >> 3;
    const int p = rest % 49;
    const int nd = rest / 49;

    const int ndkv = ((nd & 7) == 7) ? nd : nd + 1;
    const int tid = threadIdx.x;
    const int wv = tid >> 6, ln = tid & 63;
    const int lane15 = ln & 15, quad = ln >> 4;

    __shared__ ushort Ks[256 * 32];   // [key][32ch]; first 9 KB reused as Ps
    __shared__ ushort Vt[32 * 264];   // [ch][key] stride 264: 16.5 KB
    ushort* Ps = Ks;                  // alias: Ks dead after QK^T (barrier'd)

    const int rb = (nd * 49 + p) * 4;
    int wid[4];
#pragma unroll
    for (int i = 0; i < 4; ++i) wid[i] = ridx[rb + i];

    const size_t kvband = (size_t)ndkv * 49;

    // ---- stage K via DMA: dest linear (base + ln*16B), source pre-swizzled.
    {
        const int key_l = wv * 16 + (ln >> 2);             // key within window
        const int ck = (ln ^ (ln >> 2) ^ (ln >> 4)) & 3;   // (ln&3) ^ swz(key_l)
#pragma unroll
        for (int i = 0; i < 4; ++i) {
            size_t trow = (kvband + wid[i]) * 64 + key_l;
            gl_lds16(kvbuf + trow * 512 + h * 32 + ck * 8,
                     &Ks[(i * 64 + wv * 16) * 32 + ln * 8]);
        }
    }

    // ---- Q B-frag from global (wave's own 16 q-rows): issue before the
    // VALU-heavy V staging so its latency hides under that work.
    const size_t qrow0 = (size_t)(nd * 49 + p) * 64;
    bf16x8 bQ = *(const bf16x8*)(qbuf + (qrow0 + wv * 16 + lane15) * 256 + h * 32 + quad * 8);

    // ---- stage V transposed: Vt[ch][key] ----
    {
        int key_l = (tid & 31) * 2;       // 0..62 within window
        int ch0 = (tid >> 5) * 4;         // 0..28
#pragma unroll
        for (int i = 0; i < 4; ++i) {
            size_t trow = (kvband + wid[i]) * 64;
            const ushort* g0 = kvbuf + (trow + key_l) * 512 + 256 + h * 32 + ch0;
            const ushort* g1 = g0 + 512;
            ushort4 a = *(const ushort4*)g0;
            ushort4 b = *(const ushort4*)g1;
            int kg = i * 64 + key_l;
            *(unsigned*)&Vt[(ch0 + 0) * 264 + kg] = (unsigned)a.x | ((unsigned)b.x << 16);
            *(unsigned*)&Vt[(ch0 + 1) * 264 + kg] = (unsigned)a.y | ((unsigned)b.y << 16);
            *(unsigned*)&Vt[(ch0 + 2) * 264 + kg] = (unsigned)a.z | ((unsigned)b.z << 16);
            *(unsigned*)&Vt[(ch0 + 3) * 264 + kg] = (unsigned)a.w | ((unsigned)b.w << 16);
        }
    }

    __syncthreads();   // drains vmcnt (K-DMA) + lgkmcnt (V writes)

    // ---- S^T = K · Q^T ; frag read undoes the chunk swizzle:
    // swz(t*16+lane15) == (lane15 ^ (lane15>>2)) & 3 (per-lane constant).
    const int ksz = (lane15 ^ (lane15 >> 2)) & 3;
    f32x4 st[16];
    __builtin_amdgcn_s_setprio(1);
#pragma unroll
    for (int t = 0; t < 16; ++t) {
        bf16x8 aK = *(const bf16x8*)&Ks[(t * 16 + lane15) * 32 + (quad ^ ksz) * 8];
        st[t] = __builtin_amdgcn_mfma_f32_16x16x32_bf16(aK, bQ, (f32x4){0.f, 0.f, 0.f, 0.f}, 0, 0, 0);
    }
    __builtin_amdgcn_s_setprio(0);

    __syncthreads();   // ALL waves done reading Ks -> safe to reuse as Ps

    // ---- softmax: bare exp2 (v_exp_f32), no max, norm deferred ----
    float sum = 0.f;
#pragma unroll
    for (int t = 0; t < 16; ++t)
#pragma unroll
        for (int r = 0; r < 4; ++r) {
            float e = __builtin_amdgcn_exp2f(st[t][r]);
            st[t][r] = e;
            sum += e;
        }
    sum += __shfl_xor(sum, 16);
    sum += __shfl_xor(sum, 32);
    const float inv = 1.f / sum;

    // ---- PV in 4 key-chunks of 64, unnormalized P through LDS (aliased) ----
    f32x4 oacc[2] = {{0.f, 0.f, 0.f, 0.f}, {0.f, 0.f, 0.f, 0.f}};
    const int prow = (wv * 16 + lane15) * 72;
#pragma unroll
    for (int cc = 0; cc < 4; ++cc) {
#pragma unroll
        for (int tt = 0; tt < 4; ++tt) {
            int t = cc * 4 + tt;
            uint2 pk;
            pk.x = pk2bf(st[t][0], st[t][1]);
            pk.y = pk2bf(st[t][2], st[t][3]);
            *(uint2*)&Ps[prow + tt * 16 + quad * 4] = pk;
        }
        __builtin_amdgcn_s_setprio(1);
#pragma unroll
        for (int kt = 0; kt < 2; ++kt) {
            bf16x8 aP = *(const bf16x8*)&Ps[prow + kt * 32 + quad * 8];
#pragma unroll
            for (int nt = 0; nt < 2; ++nt) {
                bf16x8 bV = *(const bf16x8*)&Vt[(nt * 16 + lane15) * 264 + cc * 64 + kt * 32 + quad * 8];
                oacc[nt] = __builtin_amdgcn_mfma_f32_16x16x32_bf16(aP, bV, oacc[nt], 0, 0, 0);
            }
        }
        __builtin_amdgcn_s_setprio(0);
    }

    // ---- store (in-place over qbuf; wave owns exactly its 16 rows) ----
#pragma unroll
    for (int nt = 0; nt < 2; ++nt)
#pragma unroll
        for (int r = 0; r < 4; ++r) {
            int row = wv * 16 + quad * 4 + r;
            qbuf[(qrow0 + row) * 256 + h * 32 + nt * 16 + lane15] = f2bf(oacc[nt][r] * inv);
        }
}

// ---------------------------------------------------------------------------
extern "C" void kernel_launch(void* const* d_in, const int* in_sizes, int n_in,
                              void* d_out, int out_size, void* d_ws, size_t ws_size,
                              hipStream_t stream) {
    const float* x    = (const float*)d_in[0];
    const float* Wqkv = (const float*)d_in[1];
    const float* bqkv = (const float*)d_in[2];
    const float* Wo   = (const float*)d_in[3];
    const float* bo   = (const float*)d_in[4];
    float* out = (float*)d_out;

    char* ws = (char*)d_ws;
    ushort* xg    = (ushort*)ws;                    ws += (size_t)50176 * 256 * 2;
    ushort* q     = (ushort*)ws;                    ws += (size_t)50176 * 256 * 2;
    ushort* kv    = (ushort*)ws;                    ws += (size_t)50176 * 512 * 2;
    ushort* Wqkvt = (ushort*)ws;                    ws += (size_t)768 * 256 * 2;
    ushort* Wot   = (ushort*)ws;                    ws += (size_t)256 * 256 * 2;
    float*  xmean = (float*)ws;                     ws += (size_t)784 * 256 * 4;
    float*  qwin  = (float*)ws;                     ws += (size_t)784 * 256 * 4;
    float*  kwin  = (float*)ws;                     ws += (size_t)784 * 256 * 4;
    int*    ridx  = (int*)ws;

    k_prep    <<<1808, 256, 0, stream>>>(x, Wqkv, Wo, xg, xmean, Wqkvt, Wot);
    k_winproj <<<dim3(8, 13), 256, 0, stream>>>(xmean, Wqkv, bqkv, qwin, kwin);
    k_route   <<<784, 256, 0, stream>>>(qwin, kwin, ridx);
    k_gemm_qkv<<<dim3(6, 392), 256, 0, stream>>>(xg, Wqkvt, bqkv, q, kv);
    k_attn    <<<dim3(8, 49, 16), 256, 0, stream>>>(q, kv, ridx);
    k_gemm_o  <<<784, 256, 0, stream>>>(q, Wot, bo, out);
}